// Round 22
// baseline (25.397 us; speedup 1.0000x reference)
//
#include <hip/hip_runtime.h>
#include <math.h>

#define N 2048
#define D 48
#define K 16
#define TILE 32
#define NT (N / TILE)              // 64 tiles per dimension
#define NBLK (NT * (NT + 1) / 2)   // 2080 upper-triangular tiles

// FROZEN numerics contract (validated r18, absmax = 1 bf16 ulp):
//   s = (q0 + q2) + q1   (plain, pinned)  — XLA SLP horizontal tree
//   g = fma(x2,y2, fma(x1,y1, fl(x0*y0))) — Eigen-FMA ascending chain
//   t1 = fl(s_n + s_m); d2 = fl(t1 - 2g)  [== fmaf(-2,g,t1), 2g exact]
//   dist = d2>0 ? sqrt(d2) : 0            [== sqrt(fmaxf(d2,0)), +0 both ways]
//   ip = fl(1-dist); den = fl(1 - fl(t2*ip))
// r21 lesson: 2x2 micro = 1 ds_read_b128/pair -> LDS-pipe co-bound (10.4us);
// 256-thr blocks -> 2080/2048 = 1.016 rounds (2x wall). This round: 128-thr
// blocks, 4x2 micro (0.75 reads/pair), 10 blocks/CU capacity -> single round.

__global__ __launch_bounds__(128, 5)
void volt_tri(const float* __restrict__ vct, const float* __restrict__ posnum,
              float* __restrict__ out) {
#pragma clang fp contract(off)
    __shared__ float4 AB[2][K * TILE];            // 16 KB staging
    float* T = reinterpret_cast<float*>(AB);      // reused as T[32][33]

    const int tid = threadIdx.x;

    // decode upper-triangular tile (by <= bx): offset(y) = y*NT - y(y-1)/2
    int t = blockIdx.x;
    int by = 0;
    while ((by + 1) * NT - ((by + 1) * by) / 2 <= t) ++by;
    const int bx = by + (t - (by * NT - (by * (by - 1)) / 2));

    const int row0 = by * TILE, col0 = bx * TILE;

    const float tau = posnum[0];
    const float lam = posnum[1];
    const float t2 = tau * tau;   // fl(tau^2)
    const float l2 = lam * lam;   // fl(lam^2)

    // stage both point sets: 2 sets x 32 rows x 16 chunks = 1024 float4 tasks
    for (int it = 0; it < 8; ++it) {
        int task = tid + 128 * it;
        int set = task >> 9;
        int rk = task & 511;
        int r = rk & 31, k = rk >> 5;
        int base = ((set ? col0 : row0) + r) * D + k * 3;
        float x0 = vct[base + 0];
        float x1 = vct[base + 1];
        float x2 = vct[base + 2];
        float q0 = x0 * x0, q1 = x1 * x1, q2 = x2 * x2;
        asm volatile("" : "+v"(q0), "+v"(q1), "+v"(q2));
        float s02 = q0 + q2;
        asm volatile("" : "+v"(s02));
        float s = s02 + q1;                    // (q0+q2)+q1, pinned plain
        AB[set][k * TILE + r] = make_float4(x0, x1, x2, s);
    }
    __syncthreads();

    const int tx = tid & 15;     // 16 col-groups
    const int ty = tid >> 4;     // 8 row-groups

    // out = 1 + G/Pd, descending-k recurrence (== ref's weighted cumprod sum
    // to ~2e-6 relative):  G_k = l2*(Pd_{k+1} + G_{k+1});  Pd_k = Pd_{k+1}*den_k
    float G[4][2], Pd[4][2];
#pragma unroll
    for (int i = 0; i < 4; ++i)
#pragma unroll
        for (int j = 0; j < 2; ++j) { G[i][j] = 0.0f; Pd[i][j] = 1.0f; }

#pragma unroll
    for (int k = K - 1; k >= 0; --k) {
        float4 a[4], b[2];
#pragma unroll
        for (int i = 0; i < 4; ++i) a[i] = AB[0][k * TILE + ty + 8 * i];
#pragma unroll
        for (int j = 0; j < 2; ++j) b[j] = AB[1][k * TILE + tx + 16 * j];
#pragma unroll
        for (int i = 0; i < 4; ++i)
#pragma unroll
            for (int j = 0; j < 2; ++j) {
                // FROZEN distance path (bit-identical micro-opt forms)
                float g = __builtin_fmaf(a[i].z, b[j].z,
                          __builtin_fmaf(a[i].y, b[j].y, a[i].x * b[j].x));
                float t1 = a[i].w + b[j].w;
                float d2 = __builtin_fmaf(-2.0f, g, t1);
                float dist = __builtin_amdgcn_sqrtf(fmaxf(d2, 0.0f));
                float ip  = 1.0f - dist;
                float den = 1.0f - t2 * ip;
                G[i][j]  = l2 * (Pd[i][j] + G[i][j]);
                Pd[i][j] = Pd[i][j] * den;
            }
    }

    // finalize values
    float val[4][2];
#pragma unroll
    for (int i = 0; i < 4; ++i)
#pragma unroll
        for (int j = 0; j < 2; ++j)
            val[i][j] = 1.0f + G[i][j] * __builtin_amdgcn_rcpf(Pd[i][j]);

    // direct store (coalesced: lanes vary tx -> consecutive columns)
#pragma unroll
    for (int i = 0; i < 4; ++i) {
        int r = ty + 8 * i;
#pragma unroll
        for (int j = 0; j < 2; ++j)
            out[(size_t)(row0 + r) * N + (col0 + tx + 16 * j)] = val[i][j];
    }

    if (bx != by) {
        __syncthreads();   // all AB reads done; safe to reuse as T
        // transpose through LDS: T[c][r] = v(r,c), stride 33 (odd -> no conflict)
#pragma unroll
        for (int i = 0; i < 4; ++i)
#pragma unroll
            for (int j = 0; j < 2; ++j)
                T[(tx + 16 * j) * 33 + (ty + 8 * i)] = val[i][j];
        __syncthreads();
        // coalesced mirror store: row (col0+rr), cols row0..row0+31
#pragma unroll
        for (int i = 0; i < 4; ++i) {
            int rr = ty + 8 * i;
#pragma unroll
            for (int j = 0; j < 2; ++j) {
                int cc = tx + 16 * j;
                out[(size_t)(col0 + rr) * N + (row0 + cc)] = T[rr * 33 + cc];
            }
        }
    }
}

extern "C" void kernel_launch(void* const* d_in, const int* in_sizes, int n_in,
                              void* d_out, int out_size, void* d_ws, size_t ws_size,
                              hipStream_t stream) {
    const float* vct    = (const float*)d_in[0];
    const float* posnum = (const float*)d_in[1];
    float* out          = (float*)d_out;

    volt_tri<<<NBLK, 128, 0, stream>>>(vct, posnum, out);
}

// Round 23
// 24.441 us; speedup vs baseline: 1.0391x; 1.0391x over previous
//
#include <hip/hip_runtime.h>
#include <math.h>

#define N 2048
#define D 48
#define K 16
#define TILE 32
#define NT (N / TILE)              // 64 tiles per dimension
#define NBLK (NT * (NT + 1) / 2)   // 2080 upper-triangular tiles
#define ROWF 52                    // padded raw-row floats (16B-aligned, bank-spread)
#define RAWSET (TILE * ROWF)       // floats per set

// FROZEN numerics contract (validated r18, absmax = 1 bf16 ulp):
//   s = (q0 + q2) + q1   (plain, pinned)  — XLA SLP horizontal tree
//   g = fma(x2,y2, fma(x1,y1, fl(x0*y0))) — Eigen-FMA ascending chain
//   t1 = fl(s_n + s_m); d2 = fmaf(-2,g,t1); dist = sqrt(fmax(d2,0))
//   ip = fl(1-dist); den = fl(1 - fl(t2*ip))
// r22 lesson: staging was 3 dword-GATHERS per task (192B lane stride) —
// ~15us of the 25us wall, constant across r18/r21/r22. This round: coalesced
// float4 loads -> padded LDS raw tile -> register repack -> AB layout.

__global__ __launch_bounds__(128, 4)
void volt_tri(const float* __restrict__ vct, const float* __restrict__ posnum,
              float* __restrict__ out) {
#pragma clang fp contract(off)
    __shared__ float4 AB[2][K * TILE];            // 16 KB
    float* Raw = reinterpret_cast<float*>(AB);    // aliased raw tile (13 KB)
    float* T   = reinterpret_cast<float*>(AB);    // aliased mirror transpose

    const int tid = threadIdx.x;

    // decode upper-triangular tile (by <= bx): offset(y) = y*NT - y(y-1)/2
    int t = blockIdx.x;
    int by = 0;
    while ((by + 1) * NT - ((by + 1) * by) / 2 <= t) ++by;
    const int bx = by + (t - (by * NT - (by * (by - 1)) / 2));

    const int row0 = by * TILE, col0 = bx * TILE;

    const float tau = posnum[0];
    const float lam = posnum[1];
    const float t2 = tau * tau;   // fl(tau^2)
    const float l2 = lam * lam;   // fl(lam^2)

    // ---- phase 1: coalesced float4 load of both 32x48 tiles into Raw ----
    // 768 tasks: set(2) x r(32) x c4(12); consecutive tid -> consecutive 16B
#pragma unroll
    for (int it = 0; it < 6; ++it) {
        int task = tid + 128 * it;
        int set = task / 384;
        int rem = task - set * 384;
        int r = rem / 12;
        int c4 = rem - r * 12;
        const float4 v = *reinterpret_cast<const float4*>(
            &vct[((set ? col0 : row0) + r) * D + c4 * 4]);
        *reinterpret_cast<float4*>(&Raw[set * RAWSET + r * ROWF + c4 * 4]) = v;
    }
    __syncthreads();

    // ---- phase 2: repack triples into registers + pinned s ----
    float rx0[8], rx1[8], rx2[8], rs[8];
#pragma unroll
    for (int it = 0; it < 8; ++it) {
        int task = tid + 128 * it;
        int set = task >> 9;
        int rk = task & 511;
        int r = rk & 31, k = rk >> 5;
        int base = set * RAWSET + r * ROWF + 3 * k;
        float x0 = Raw[base + 0];
        float x1 = Raw[base + 1];
        float x2 = Raw[base + 2];
        float q0 = x0 * x0, q1 = x1 * x1, q2 = x2 * x2;
        asm volatile("" : "+v"(q0), "+v"(q1), "+v"(q2));
        float s02 = q0 + q2;
        asm volatile("" : "+v"(s02));
        rs[it] = s02 + q1;                 // (q0+q2)+q1, pinned plain (FROZEN)
        rx0[it] = x0; rx1[it] = x1; rx2[it] = x2;
    }
    __syncthreads();   // all Raw reads done; AB may now overwrite the alias

    // ---- phase 3: write AB layout ----
#pragma unroll
    for (int it = 0; it < 8; ++it) {
        int task = tid + 128 * it;
        int set = task >> 9;
        int rk = task & 511;
        int r = rk & 31, k = rk >> 5;
        AB[set][k * TILE + r] = make_float4(rx0[it], rx1[it], rx2[it], rs[it]);
    }
    __syncthreads();

    const int tx = tid & 15;     // 16 col-groups
    const int ty = tid >> 4;     // 8 row-groups

    // out = 1 + G/Pd, descending-k recurrence (== ref's weighted cumprod sum
    // to ~2e-6 relative):  G_k = l2*(Pd_{k+1} + G_{k+1});  Pd_k = Pd_{k+1}*den_k
    float G[4][2], Pd[4][2];
#pragma unroll
    for (int i = 0; i < 4; ++i)
#pragma unroll
        for (int j = 0; j < 2; ++j) { G[i][j] = 0.0f; Pd[i][j] = 1.0f; }

#pragma unroll
    for (int k = K - 1; k >= 0; --k) {
        float4 a[4], b[2];
#pragma unroll
        for (int i = 0; i < 4; ++i) a[i] = AB[0][k * TILE + ty + 8 * i];
#pragma unroll
        for (int j = 0; j < 2; ++j) b[j] = AB[1][k * TILE + tx + 16 * j];
#pragma unroll
        for (int i = 0; i < 4; ++i)
#pragma unroll
            for (int j = 0; j < 2; ++j) {
                // FROZEN distance path
                float g = __builtin_fmaf(a[i].z, b[j].z,
                          __builtin_fmaf(a[i].y, b[j].y, a[i].x * b[j].x));
                float t1 = a[i].w + b[j].w;
                float d2 = __builtin_fmaf(-2.0f, g, t1);
                float dist = __builtin_amdgcn_sqrtf(fmaxf(d2, 0.0f));
                float ip  = 1.0f - dist;
                float den = 1.0f - t2 * ip;
                G[i][j]  = l2 * (Pd[i][j] + G[i][j]);
                Pd[i][j] = Pd[i][j] * den;
            }
    }

    // finalize values
    float val[4][2];
#pragma unroll
    for (int i = 0; i < 4; ++i)
#pragma unroll
        for (int j = 0; j < 2; ++j)
            val[i][j] = 1.0f + G[i][j] * __builtin_amdgcn_rcpf(Pd[i][j]);

    // direct store (coalesced: lanes vary tx -> consecutive columns)
#pragma unroll
    for (int i = 0; i < 4; ++i) {
        int r = ty + 8 * i;
#pragma unroll
        for (int j = 0; j < 2; ++j)
            out[(size_t)(row0 + r) * N + (col0 + tx + 16 * j)] = val[i][j];
    }

    if (bx != by) {
        __syncthreads();   // all AB reads done; safe to reuse as T
        // transpose through LDS: T[c][r] = v(r,c), stride 33 (odd -> no conflict)
#pragma unroll
        for (int i = 0; i < 4; ++i)
#pragma unroll
            for (int j = 0; j < 2; ++j)
                T[(tx + 16 * j) * 33 + (ty + 8 * i)] = val[i][j];
        __syncthreads();
        // coalesced mirror store: row (col0+rr), cols row0..row0+31
#pragma unroll
        for (int i = 0; i < 4; ++i) {
            int rr = ty + 8 * i;
#pragma unroll
            for (int j = 0; j < 2; ++j) {
                int cc = tx + 16 * j;
                out[(size_t)(col0 + rr) * N + (row0 + cc)] = T[rr * 33 + cc];
            }
        }
    }
}

extern "C" void kernel_launch(void* const* d_in, const int* in_sizes, int n_in,
                              void* d_out, int out_size, void* d_ws, size_t ws_size,
                              hipStream_t stream) {
    const float* vct    = (const float*)d_in[0];
    const float* posnum = (const float*)d_in[1];
    float* out          = (float*)d_out;

    volt_tri<<<NBLK, 128, 0, stream>>>(vct, posnum, out);
}